// Round 10
// baseline (721.445 us; speedup 1.0000x reference)
//
#include <hip/hip_runtime.h>
#include <stdint.h>

// ---------------------------------------------------------------------------
// ResidueGraphModel: aanet_proj (512->1024->1024->512->80, ReLU) -> in_net
// (80->512) -> GIN sum-aggregation + MLP (512->512->512) -> out_net (512->80).
// R18: faithful m201 8-phase port, applied to L2 ONLY (A/B vs the 128^2 body
// at 122us/37% MfmaUtil). Prior attempts failed for identified reasons:
// R10 double-read frags (48 ds_read/K-tile), R11 coarse 2-phase (m196's
// anti-pattern). This is the validated schedule: 4 phases/K-tile, 16 MFMA
// per phase (one 64x32 C-quadrant), per phase {frag ds_reads | stage exactly
// 1 half-tile (2 gload)} -> barrier -> lgkmcnt(0) -> setprio+16 MFMA ->
// barrier; counted vmcnt(4) once per K-tile at q3. Stagger hand-verified:
// A-halves last ds_read at q2 -> A(a+1) staged q0/q1 (other slot, content
// dead since q2(a-1)); B-halves last read q1 -> B(a+2) staged q2/q3 (same
// slot, after q1's barrier). vmcnt(4)@q3(a) leaves only B(a+2) halves in
// flight => tile a+1 fully landed. Prologue: 6 half-tiles + vmcnt(4).
// Tails: vmcnt(0) at a=nkt-2. nkt=16 for L2.
// R17 (kept): 64x128 body for L4/L8; preprocess grain; R16 atomic-free
// scatter; R14 128^2+(256,4) body everywhere else.
// Outputs fp32: d_out = [peptide_mask (N*80) | peptide_feat (N*80)].
// ---------------------------------------------------------------------------

using bf16x8 = __attribute__((ext_vector_type(8))) short;
using f32x4  = __attribute__((ext_vector_type(4))) float;

__device__ inline unsigned short f2bf(float f) {
    union { float f; unsigned u; } v; v.f = f;
    unsigned u = v.u;
    u += 0x7FFFu + ((u >> 16) & 1u);   // RNE
    return (unsigned short)(u >> 16);
}
__device__ inline float bf2f(unsigned u16) {
    return __uint_as_float(u16 << 16);
}

// ------------- merged preprocessing ----------------------------------------
struct PreDescs {
    const float* W[8]; unsigned short* Wt[8];
    int K[8], M[8], Kp[8], ntx[8], start[8];
    int tEnd, cEnd, eEnd;
    const float* feat; unsigned short* featb; int nFeat;
    const int* ei; int E; int* cnt; int* rank;
};

__global__ __launch_bounds__(256) void rg_preprocess(PreDescs d) {
    int b = blockIdx.x;
    int tid = threadIdx.x;
    if (b < d.tEnd) {
        __shared__ float t[32][33];
        int di = 0;
#pragma unroll
        for (int i = 1; i < 8; ++i) if (b >= d.start[i]) di = i;
        int local = b - d.start[di];
        int bx = local % d.ntx[di];
        int by = local / d.ntx[di];
        const float* W = d.W[di];
        unsigned short* Wt = d.Wt[di];
        int K = d.K[di], M = d.M[di], Kp = d.Kp[di];
        int mb = bx * 32, kb = by * 32;
        int tx = tid & 31, tg = tid >> 5;
#pragma unroll
        for (int p = 0; p < 4; ++p) {
            int r = tg + p * 8;
            int k = kb + r, m = mb + tx;
            t[r][tx] = (k < K && m < M) ? W[(size_t)k * M + m] : 0.f;
        }
        __syncthreads();
#pragma unroll
        for (int p = 0; p < 4; ++p) {
            int r = tg + p * 8;
            int mo = mb + r, ko = kb + tx;
            Wt[(size_t)mo * Kp + ko] = f2bf(t[tx][r]);
        }
    } else if (b < d.cEnd) {
        int base = (b - d.tEnd) * 4096 + tid * 4;   // 16 elems/thread
#pragma unroll
        for (int p = 0; p < 4; ++p) {
            int i = base + p * 1024;
            if (i + 3 < d.nFeat) {
                float4 v = *(const float4*)(d.feat + i);
                ushort4 o; o.x = f2bf(v.x); o.y = f2bf(v.y); o.z = f2bf(v.z); o.w = f2bf(v.w);
                *(ushort4*)(d.featb + i) = o;
            }
        }
    } else {
        int e0 = (b - d.cEnd) * 1024 + tid;         // 4 edges/thread
#pragma unroll
        for (int p = 0; p < 4; ++p) {
            int e = e0 + p * 256;
            if (e < d.E) {
                int dd = d.ei[d.E + e];
                d.rank[e] = atomicAdd(&d.cnt[dd], 1);
            }
        }
    }
}

// ---------------- 128x128 GEMM body (single-buffer) -------------------------
template <bool RELU, bool OUT_BF, bool OUT_F32, bool DEGB, int MT>
__device__ __forceinline__ void gemm_body(
    int bid,
    const unsigned short* __restrict__ A, const unsigned short* __restrict__ Bt,
    const float* __restrict__ bias, const int* __restrict__ deg, int Mvalid,
    unsigned short* __restrict__ outB, float* __restrict__ outF,
    int Nrows, int Kp, int Mp, int gN)
{
    __shared__ __align__(16) unsigned short As[128 * 64];
    __shared__ __align__(16) unsigned short Bs[128 * 64];

    int xcd = bid & 7;
    int slot = bid >> 3;
    int c = slot % MT;
    int rsub = slot / MT;
    int rt = rsub * 8 + xcd;
    if (rt >= gN) return;
    const int rowBase = rt * 128;
    const int nBase   = c * 128;

    const int tid  = threadIdx.x;
    const int lane = tid & 63;
    const int w    = tid >> 6;
    const int wm   = w & 1, wn = w >> 1;

    f32x4 acc[4][4];
#pragma unroll
    for (int i = 0; i < 4; ++i)
#pragma unroll
        for (int j = 0; j < 4; ++j) acc[i][j] = (f32x4){0.f, 0.f, 0.f, 0.f};

    const int nkt = Kp >> 6;
    for (int kt = 0; kt < nkt; ++kt) {
        __syncthreads();
        const int k0 = kt * 64;
#pragma unroll
        for (int i = 0; i < 4; ++i) {
            int q   = i * 256 + tid;
            int r   = q >> 3;
            int cbg = (q & 7) ^ (r & 7);
            const unsigned short* gp = A + (size_t)(rowBase + r) * Kp + k0 + cbg * 8;
            __builtin_amdgcn_global_load_lds(
                (const __attribute__((address_space(1))) void*)gp,
                (__attribute__((address_space(3))) void*)(&As[q * 8]), 16, 0, 0);
        }
#pragma unroll
        for (int i = 0; i < 4; ++i) {
            int q   = i * 256 + tid;
            int r   = q >> 3;
            int cbg = (q & 7) ^ (r & 7);
            const unsigned short* gp = Bt + (size_t)(nBase + r) * Kp + k0 + cbg * 8;
            __builtin_amdgcn_global_load_lds(
                (const __attribute__((address_space(1))) void*)gp,
                (__attribute__((address_space(3))) void*)(&Bs[q * 8]), 16, 0, 0);
        }
        __syncthreads();
#pragma unroll
        for (int kk = 0; kk < 2; ++kk) {
            bf16x8 a[4], b[4];
            const int cb = kk * 4 + (lane >> 4);
#pragma unroll
            for (int i = 0; i < 4; ++i) {
                int r = wm * 64 + i * 16 + (lane & 15);
                a[i] = *(const bf16x8*)&As[(r * 8 + (cb ^ (r & 7))) * 8];
            }
#pragma unroll
            for (int j = 0; j < 4; ++j) {
                int r = wn * 64 + j * 16 + (lane & 15);
                b[j] = *(const bf16x8*)&Bs[(r * 8 + (cb ^ (r & 7))) * 8];
            }
#pragma unroll
            for (int i = 0; i < 4; ++i)
#pragma unroll
                for (int j = 0; j < 4; ++j)
                    acc[i][j] = __builtin_amdgcn_mfma_f32_16x16x32_bf16(b[j], a[i], acc[i][j], 0, 0, 0);
        }
    }

    const int quad = lane >> 4;
#pragma unroll
    for (int i = 0; i < 4; ++i) {
        int row = rowBase + wm * 64 + i * 16 + (lane & 15);
        if (row >= Nrows) continue;
        float sc = 1.f;
        if (DEGB) sc = 1.f + (float)deg[row];
#pragma unroll
        for (int j = 0; j < 4; ++j) {
            int colb = nBase + wn * 64 + j * 16 + quad * 4;
            float4 bv = (colb < Mvalid) ? *(const float4*)(bias + colb)
                                        : (float4){0.f, 0.f, 0.f, 0.f};
            float v0 = acc[i][j][0] + sc * bv.x;
            float v1 = acc[i][j][1] + sc * bv.y;
            float v2 = acc[i][j][2] + sc * bv.z;
            float v3 = acc[i][j][3] + sc * bv.w;
            if (RELU) {
                v0 = v0 > 0.f ? v0 : 0.f; v1 = v1 > 0.f ? v1 : 0.f;
                v2 = v2 > 0.f ? v2 : 0.f; v3 = v3 > 0.f ? v3 : 0.f;
            }
            if (OUT_BF) {
                ushort4 o; o.x = f2bf(v0); o.y = f2bf(v1); o.z = f2bf(v2); o.w = f2bf(v3);
                *(ushort4*)(outB + (size_t)row * Mp + colb) = o;
            }
            if (OUT_F32) {
                if (colb < Mvalid)
                    *(float4*)(outF + (size_t)row * Mvalid + colb) = (float4){v0, v1, v2, v3};
            }
        }
    }
}

template <bool RELU, bool OUT_BF, bool OUT_F32, bool DEGB, int MT>
__global__ __launch_bounds__(256, 4) void rg_gemm(
    const unsigned short* __restrict__ A, const unsigned short* __restrict__ Bt,
    const float* __restrict__ bias, const int* __restrict__ deg, int Mvalid,
    unsigned short* __restrict__ outB, float* __restrict__ outF,
    int Nrows, int Kp, int Mp, int gN)
{
    gemm_body<RELU, OUT_BF, OUT_F32, DEGB, MT>(blockIdx.x, A, Bt, bias, deg,
                                               Mvalid, outB, outF, Nrows, Kp, Mp, gN);
}

// ---------------- 256x256 4-phase/K-tile GEMM (m201 schedule, R18) ----------
// 8 waves = 2(wm) x 4(wn); wave output 128x64 (rows wm*128.., cols wn*64..).
// LDS: As[2][2][128x64], Bs[2][2][128x64] (dbuf slot x half), 128 KiB.
// Phase q of K-tile a (quadrant rh=q>>1, ch=q&1): frag ds_reads + stage one
// half-tile, barrier, lgkmcnt(0), 16 MFMA, barrier. vmcnt(4) at q3 only.
template <bool RELU, int MT>
__global__ __launch_bounds__(512, 2) void rg_gemm256_8ph(
    const unsigned short* __restrict__ A, const unsigned short* __restrict__ Bt,
    const float* __restrict__ bias, unsigned short* __restrict__ outB,
    int Nrows, int NrowsPad, int Kp, int Mp, int gN2)
{
    __shared__ __align__(16) unsigned short As[2][2][128 * 64];
    __shared__ __align__(16) unsigned short Bs[2][2][128 * 64];

    int bid = blockIdx.x;
    int xcd = bid & 7;
    int slotb = bid >> 3;
    int c = slotb % MT;
    int rsub = slotb / MT;
    int rt = rsub * 8 + xcd;
    if (rt >= gN2) return;
    const int rowBase = rt * 256;
    const int nBase   = c * 256;

    const int tid  = threadIdx.x;
    const int lane = tid & 63;
    const int w    = tid >> 6;
    const int wm   = w & 1;          // row half (128 rows)
    const int wn   = w >> 1;         // col group (64 cols)
    const int hb   = wn >> 1;        // B half
    const int wc   = wn & 1;         // col offset within B half
    const int lane15 = lane & 15;
    const int laneq  = lane >> 4;

    f32x4 acc[8][4];
#pragma unroll
    for (int i = 0; i < 8; ++i)
#pragma unroll
        for (int j = 0; j < 4; ++j) acc[i][j] = (f32x4){0.f, 0.f, 0.f, 0.f};

    const int nkt = Kp >> 6;

    auto stageA = [&](int t, int hf) {
        const int k0 = t << 6;
        unsigned short* dst = &As[t & 1][hf][0];
#pragma unroll
        for (int ld = 0; ld < 2; ++ld) {
            int q   = ld * 512 + tid;
            int r   = q >> 3;
            int cbg = (q & 7) ^ (r & 7);
            int grow = rowBase + hf * 128 + r;
            grow = grow < NrowsPad ? grow : NrowsPad - 1;
            const unsigned short* gp = A + (size_t)grow * Kp + k0 + cbg * 8;
            __builtin_amdgcn_global_load_lds(
                (const __attribute__((address_space(1))) void*)gp,
                (__attribute__((address_space(3))) void*)(dst + q * 8), 16, 0, 0);
        }
    };
    auto stageB = [&](int t, int hf) {
        const int k0 = t << 6;
        unsigned short* dst = &Bs[t & 1][hf][0];
#pragma unroll
        for (int ld = 0; ld < 2; ++ld) {
            int q   = ld * 512 + tid;
            int r   = q >> 3;
            int cbg = (q & 7) ^ (r & 7);
            const unsigned short* gp = Bt + (size_t)(nBase + hf * 128 + r) * Kp + k0 + cbg * 8;
            __builtin_amdgcn_global_load_lds(
                (const __attribute__((address_space(1))) void*)gp,
                (__attribute__((address_space(3))) void*)(dst + q * 8), 16, 0, 0);
        }
    };

    bf16x8 av[4][2];                 // current quadrant-row A frags (reloaded q0,q2)
    bf16x8 bv0[2][2], bv1[2][2];     // B frags ch0/ch1 (persist per K-tile)

    auto readA = [&](int slot, int rh) {
#pragma unroll
        for (int i = 0; i < 4; ++i) {
            int lr = rh * 64 + i * 16 + lane15;
#pragma unroll
            for (int kk = 0; kk < 2; ++kk) {
                int cb = kk * 4 + laneq;
                av[i][kk] = *(const bf16x8*)&As[slot][wm][(lr * 8 + (cb ^ (lr & 7))) * 8];
            }
        }
    };
    auto readB = [&](int slot, int ch, bf16x8 bv[2][2]) {
#pragma unroll
        for (int j = 0; j < 2; ++j) {
            int lc = wc * 64 + ch * 32 + j * 16 + lane15;
#pragma unroll
            for (int kk = 0; kk < 2; ++kk) {
                int cb = kk * 4 + laneq;
                bv[j][kk] = *(const bf16x8*)&Bs[slot][hb][(lc * 8 + (cb ^ (lc & 7))) * 8];
            }
        }
    };
    auto mfma16 = [&](int rh, int ch, bf16x8 bv[2][2]) {
        __builtin_amdgcn_s_setprio(1);
#pragma unroll
        for (int i = 0; i < 4; ++i)
#pragma unroll
            for (int j = 0; j < 2; ++j)
#pragma unroll
                for (int kk = 0; kk < 2; ++kk)
                    acc[rh * 4 + i][ch * 2 + j] = __builtin_amdgcn_mfma_f32_16x16x32_bf16(
                        bv[j][kk], av[i][kk], acc[rh * 4 + i][ch * 2 + j], 0, 0, 0);
        __builtin_amdgcn_s_setprio(0);
    };

#define RG_SYNC_IN  do { __builtin_amdgcn_sched_barrier(0); __builtin_amdgcn_s_barrier(); \
                         asm volatile("s_waitcnt lgkmcnt(0)" ::: "memory"); \
                         __builtin_amdgcn_sched_barrier(0); } while (0)
#define RG_SYNC_OUT do { __builtin_amdgcn_sched_barrier(0); __builtin_amdgcn_s_barrier(); } while (0)

    // prologue: tile0 complete + B halves of tile1 (12 loads); vmcnt(4)
    stageA(0, 0); stageB(0, 0); stageB(0, 1); stageA(0, 1);
    stageB(1, 0); stageB(1, 1);
    asm volatile("s_waitcnt vmcnt(4)" ::: "memory");
    __builtin_amdgcn_sched_barrier(0);
    __builtin_amdgcn_s_barrier();
    __builtin_amdgcn_sched_barrier(0);

    for (int a = 0; a < nkt; ++a) {
        const int slot = a & 1;
        // q0: quadrant (0,0) -- read A-rh0 + B-ch0; stage A0(a+1)
        readA(slot, 0);
        readB(slot, 0, bv0);
        if (a + 1 < nkt) stageA(a + 1, 0);
        RG_SYNC_IN;
        mfma16(0, 0, bv0);
        RG_SYNC_OUT;
        // q1: quadrant (0,1) -- read B-ch1; stage A1(a+1)
        readB(slot, 1, bv1);
        if (a + 1 < nkt) stageA(a + 1, 1);
        RG_SYNC_IN;
        mfma16(0, 1, bv1);
        RG_SYNC_OUT;
        // q2: quadrant (1,0) -- read A-rh1; stage B0(a+2)
        readA(slot, 1);
        if (a + 2 < nkt) stageB(a + 2, 0);
        RG_SYNC_IN;
        mfma16(1, 0, bv0);
        RG_SYNC_OUT;
        // q3: quadrant (1,1) -- no reads; stage B1(a+2) + counted vmcnt
        if (a + 2 < nkt) {
            stageB(a + 2, 1);
            asm volatile("s_waitcnt vmcnt(4)" ::: "memory");   // tile a+1 landed
        } else if (a + 1 < nkt) {
            asm volatile("s_waitcnt vmcnt(0)" ::: "memory");   // tail drain
        }
        RG_SYNC_IN;
        mfma16(1, 1, bv1);
        RG_SYNC_OUT;
    }
#undef RG_SYNC_IN
#undef RG_SYNC_OUT

    // epilogue: row = rowBase + wm*128 + mi*16 + lane15; col = nBase + wn*64 + nj*16 + quad*4
    const int quad = lane >> 4;
#pragma unroll
    for (int mi = 0; mi < 8; ++mi) {
        int row = rowBase + wm * 128 + mi * 16 + lane15;
        if (row >= Nrows) continue;
#pragma unroll
        for (int nj = 0; nj < 4; ++nj) {
            int colb = nBase + wn * 64 + nj * 16 + quad * 4;
            float4 bvv = *(const float4*)(bias + colb);
            float v0 = acc[mi][nj][0] + bvv.x;
            float v1 = acc[mi][nj][1] + bvv.y;
            float v2 = acc[mi][nj][2] + bvv.z;
            float v3 = acc[mi][nj][3] + bvv.w;
            if (RELU) {
                v0 = v0 > 0.f ? v0 : 0.f; v1 = v1 > 0.f ? v1 : 0.f;
                v2 = v2 > 0.f ? v2 : 0.f; v3 = v3 > 0.f ? v3 : 0.f;
            }
            ushort4 o; o.x = f2bf(v0); o.y = f2bf(v1); o.z = f2bf(v2); o.w = f2bf(v3);
            *(ushort4*)(outB + (size_t)row * Mp + colb) = o;
        }
    }
}

// ---------------- 64x128 GEMM body (M=128 latency-bound layers) -------------
template <bool RELU, bool OUT_BF, bool OUT_F32, int MT>
__global__ __launch_bounds__(256, 4) void rg_gemm64(
    const unsigned short* __restrict__ A, const unsigned short* __restrict__ Bt,
    const float* __restrict__ bias, int Mvalid,
    unsigned short* __restrict__ outB, float* __restrict__ outF,
    int Nrows, int Kp, int Mp, int gN64)
{
    __shared__ __align__(16) unsigned short As[64 * 64];
    __shared__ __align__(16) unsigned short Bs[128 * 64];

    int bid = blockIdx.x;
    int xcd = bid & 7;
    int slot = bid >> 3;
    int c = slot % MT;
    int rsub = slot / MT;
    int rt = rsub * 8 + xcd;
    if (rt >= gN64) return;
    const int rowBase = rt * 64;
    const int nBase   = c * 128;

    const int tid  = threadIdx.x;
    const int lane = tid & 63;
    const int wn   = tid >> 6;

    f32x4 acc[4][2];
#pragma unroll
    for (int i = 0; i < 4; ++i)
#pragma unroll
        for (int j = 0; j < 2; ++j) acc[i][j] = (f32x4){0.f, 0.f, 0.f, 0.f};

    const int nkt = Kp >> 6;
    for (int kt = 0; kt < nkt; ++kt) {
        __syncthreads();
        const int k0 = kt * 64;
#pragma unroll
        for (int i = 0; i < 2; ++i) {
            int q   = i * 256 + tid;
            int r   = q >> 3;
            int cbg = (q & 7) ^ (r & 7);
            const unsigned short* gp = A + (size_t)(rowBase + r) * Kp + k0 + cbg * 8;
            __builtin_amdgcn_global_load_lds(
                (const __attribute__((address_space(1))) void*)gp,
                (__attribute__((address_space(3))) void*)(&As[q * 8]), 16, 0, 0);
        }
#pragma unroll
        for (int i = 0; i < 4; ++i) {
            int q   = i * 256 + tid;
            int r   = q >> 3;
            int cbg = (q & 7) ^ (r & 7);
            const unsigned short* gp = Bt + (size_t)(nBase + r) * Kp + k0 + cbg * 8;
            __builtin_amdgcn_global_load_lds(
                (const __attribute__((address_space(1))) void*)gp,
                (__attribute__((address_space(3))) void*)(&Bs[q * 8]), 16, 0, 0);
        }
        __syncthreads();
#pragma unroll
        for (int kk = 0; kk < 2; ++kk) {
            bf16x8 a[4], b[2];
            const int cb = kk * 4 + (lane >> 4);
#pragma unroll
            for (int i = 0; i < 4; ++i) {
                int r = i * 16 + (lane & 15);
                a[i] = *(const bf16x8*)&As[(r * 8 + (cb ^ (r & 7))) * 8];
            }
#pragma unroll
            for (int j = 0; j < 2; ++j) {
                int r = wn * 32 + j * 16 + (lane & 15);
                b[j] = *(const bf16x8*)&Bs[(r * 8 + (cb ^ (r & 7))) * 8];
            }
#pragma unroll
            for (int i = 0; i < 4; ++i)
#pragma unroll
                for (int j = 0; j < 2; ++j)
                    acc[i][j] = __builtin_amdgcn_mfma_f32_16x16x32_bf16(b[j], a[i], acc[i][j], 0, 0, 0);
        }
    }

    const int quad = lane >> 4;
#pragma unroll
    for (int i = 0; i < 4; ++i) {
        int row = rowBase + i * 16 + (lane & 15);
        if (row >= Nrows) continue;
#pragma unroll
        for (int j = 0; j < 2; ++j) {
            int colb = nBase + wn * 32 + j * 16 + quad * 4;
            float4 bv = (colb < Mvalid) ? *(const float4*)(bias + colb)
                                        : (float4){0.f, 0.f, 0.f, 0.f};
            float v0 = acc[i][j][0] + bv.x;
            float v1 = acc[i][j][1] + bv.y;
            float v2 = acc[i][j][2] + bv.z;
            float v3 = acc[i][j][3] + bv.w;
            if (RELU) {
                v0 = v0 > 0.f ? v0 : 0.f; v1 = v1 > 0.f ? v1 : 0.f;
                v2 = v2 > 0.f ? v2 : 0.f; v3 = v3 > 0.f ? v3 : 0.f;
            }
            if (OUT_BF) {
                ushort4 o; o.x = f2bf(v0); o.y = f2bf(v1); o.z = f2bf(v2); o.w = f2bf(v3);
                *(ushort4*)(outB + (size_t)row * Mp + colb) = o;
            }
            if (OUT_F32) {
                if (colb < Mvalid)
                    *(float4*)(outF + (size_t)row * Mvalid + colb) = (float4){v0, v1, v2, v3};
            }
        }
    }
}

// L1 GEMM + edge scatter in one dispatch (trailing layout, atomic-free)
__global__ __launch_bounds__(256, 4) void rg_gemm_l1_scatter(
    const unsigned short* __restrict__ A, const unsigned short* __restrict__ Bt,
    const float* __restrict__ bias, int Mvalid,
    unsigned short* __restrict__ outB, int Nrows, int Kp, int Mp, int gN,
    int gemmBlocks, const int* __restrict__ ei, int E,
    const int* __restrict__ rowptr, const int* __restrict__ rank,
    int* __restrict__ cols)
{
    int bid = blockIdx.x;
    if (bid < gemmBlocks) {
        gemm_body<true, true, false, false, 8>(bid, A, Bt, bias, nullptr,
                                               Mvalid, outB, nullptr, Nrows, Kp, Mp, gN);
    } else {
        int e = (bid - gemmBlocks) * 256 + threadIdx.x;
        if (e < E) {
            int d = ei[E + e];
            int p = rowptr[d] + rank[e];
            cols[p] = ei[e];
        }
    }
}

// ---------------- merged scan ------------------------------------------------
__device__ __forceinline__ void rg_gridbar(int* bar, int nb, int phase) {
    __syncthreads();
    if (threadIdx.x == 0) {
        __threadfence();
        atomicAdd(bar, 1);
        int target = phase * nb;
        while (__hip_atomic_load(bar, __ATOMIC_RELAXED, __HIP_MEMORY_SCOPE_AGENT) < target) {}
        __threadfence();
    }
    __syncthreads();
}

__global__ __launch_bounds__(1024) void rg_scan_all(
    const int* __restrict__ cnt, int* __restrict__ rowptr,
    int* __restrict__ bsums, int* bar, int Nn, int E, int nb)
{
    __shared__ int sd[1024];
    const int tid = threadIdx.x;
    const int bid = blockIdx.x;
    const int i   = bid * 1024 + tid;

    int v = (i < Nn) ? cnt[i] : 0;
    sd[tid] = v;
    __syncthreads();
    for (int off = 1; off < 1024; off <<= 1) {
        int t = (tid >= off) ? sd[tid - off] : 0;
        __syncthreads();
        sd[tid] += t;
        __syncthreads();
    }
    if (tid == 1023) bsums[bid] = sd[1023];
    rg_gridbar(bar, nb, 1);

    if (bid == 0 && tid < 64) {
        int bv = (tid < nb) ? bsums[tid] : 0;
        int incl = bv;
#pragma unroll
        for (int off = 1; off < 64; off <<= 1) {
            int t = __shfl_up(incl, off, 64);
            if (tid >= off) incl += t;
        }
        if (tid < nb) bsums[tid] = incl - bv;
    }
    rg_gridbar(bar, nb, 2);

    if (i < Nn) {
        int ex = sd[tid] - v + bsums[bid];
        rowptr[i] = ex;
    }
    if (i == 0) rowptr[Nn] = E;
}

// ---------------- 80-dim aggregation ----------------------------------------
__global__ __launch_bounds__(256) void rg_agg80(
    const unsigned short* __restrict__ pf, const int* __restrict__ rowptr,
    const int* __restrict__ cols, unsigned short* __restrict__ s, int Nn)
{
    int node = blockIdx.x * 4 + (threadIdx.x >> 6);
    if (node >= Nn) return;
    int lane = threadIdx.x & 63;
    const unsigned* xp = (const unsigned*)pf;
    size_t off = (size_t)node * 64 + lane;
    unsigned u = xp[off];
    float a0 = bf2f(u & 0xffffu), a1 = bf2f(u >> 16);
    int beg = rowptr[node], end = rowptr[node + 1];
    int e = beg;
    for (; e + 8 <= end; e += 8) {
        unsigned v[8];
#pragma unroll
        for (int t = 0; t < 8; ++t) v[t] = xp[(size_t)cols[e + t] * 64 + lane];
#pragma unroll
        for (int t = 0; t < 8; ++t) { a0 += bf2f(v[t] & 0xffffu); a1 += bf2f(v[t] >> 16); }
    }
    for (; e < end; ++e) {
        unsigned v = xp[(size_t)cols[e] * 64 + lane];
        a0 += bf2f(v & 0xffffu); a1 += bf2f(v >> 16);
    }
    unsigned o = (unsigned)f2bf(a0) | ((unsigned)f2bf(a1) << 16);
    ((unsigned*)s)[off] = o;
}

// ---------------------------------------------------------------------------
extern "C" void kernel_launch(void* const* d_in, const int* in_sizes, int n_in,
                              void* d_out, int out_size, void* d_ws, size_t ws_size,
                              hipStream_t stream)
{
    const float* feat = (const float*)d_in[0];
    const int*   ei   = (const int*)d_in[1];
    const float* W1 = (const float*)d_in[2];  const float* b1 = (const float*)d_in[3];
    const float* W2 = (const float*)d_in[4];  const float* b2 = (const float*)d_in[5];
    const float* W3 = (const float*)d_in[6];  const float* b3 = (const float*)d_in[7];
    const float* W4 = (const float*)d_in[8];  const float* b4 = (const float*)d_in[9];
    const float* Wi = (const float*)d_in[10]; const float* bi = (const float*)d_in[11];
    const float* Wg1 = (const float*)d_in[12]; const float* bg1 = (const float*)d_in[13];
    const float* Wg2 = (const float*)d_in[14]; const float* bg2 = (const float*)d_in[15];
    const float* Wo = (const float*)d_in[16]; const float* bo = (const float*)d_in[17];

    const int N = in_sizes[0] / 512;   // 50000
    const int E = in_sizes[1] / 2;     // 800000
    const int gN = (N + 127) / 128;    // 391
    const int Npad = gN * 128;         // 50048

    char* ws = (char*)d_ws;
    size_t o = 0;
    auto alloc = [&](size_t bytes) { char* p = ws + o; o += (bytes + 255) & ~(size_t)255; return p; };
    unsigned short* bufA = (unsigned short*)alloc((size_t)Npad * 1024 * 2); // h1 / pf / g
    unsigned short* bufB = (unsigned short*)alloc((size_t)Npad * 1024 * 2); // h2 / r1
    unsigned short* bufC = (unsigned short*)alloc((size_t)Npad * 512 * 2);  // A0 / h3 / s / g2
    unsigned short* W1t = (unsigned short*)alloc((size_t)1024 * 512 * 2);
    unsigned short* W2t = (unsigned short*)alloc((size_t)1024 * 1024 * 2);
    unsigned short* W3t = (unsigned short*)alloc((size_t)512 * 1024 * 2);
    unsigned short* W4t = (unsigned short*)alloc((size_t)128 * 512 * 2);
    unsigned short* Wit = (unsigned short*)alloc((size_t)512 * 128 * 2);
    unsigned short* Wg1t = (unsigned short*)alloc((size_t)512 * 512 * 2);
    unsigned short* Wg2t = (unsigned short*)alloc((size_t)512 * 512 * 2);
    unsigned short* Wot = (unsigned short*)alloc((size_t)128 * 512 * 2);
    int* cnt    = (int*)alloc((size_t)(N + 64) * 4);
    int* bar    = cnt + N;
    int* rowptr = (int*)alloc((size_t)(N + 1) * 4);
    int* rank   = (int*)alloc((size_t)E * 4);
    int* cols   = (int*)alloc((size_t)E * 4);
    int* bsums  = (int*)alloc(256);

    float* out_mask = (float*)d_out;                  // [N,80]
    float* out_feat = (float*)d_out + (size_t)N * 80; // [N,80]

    // ---- merged preprocessing ----
    hipMemsetAsync(cnt, 0, (size_t)(N + 64) * 4, stream);
    {
        PreDescs d;
        const float* Ws[8]  = {W1, W2, W3, W4, Wi, Wg1, Wg2, Wo};
        unsigned short* Ts[8] = {W1t, W2t, W3t, W4t, Wit, Wg1t, Wg2t, Wot};
        int Ks[8]  = {512, 1024, 1024, 512, 80, 512, 512, 512};
        int Ms[8]  = {1024, 1024, 512, 80, 512, 512, 512, 80};
        int Kps[8] = {512, 1024, 1024, 512, 128, 512, 512, 512};
        int Mps[8] = {1024, 1024, 512, 128, 512, 512, 512, 128};
        int st = 0;
        for (int i = 0; i < 8; ++i) {
            d.W[i] = Ws[i]; d.Wt[i] = Ts[i];
            d.K[i] = Ks[i]; d.M[i] = Ms[i]; d.Kp[i] = Kps[i];
            d.ntx[i] = Mps[i] / 32;
            d.start[i] = st;
            st += (Mps[i] / 32) * (Kps[i] / 32);
        }
        d.tEnd = st;
        d.cEnd = st + (N * 512) / 4096;
        d.eEnd = d.cEnd + (E + 1023) / 1024;
        d.feat = feat; d.featb = bufC; d.nFeat = N * 512;
        d.ei = ei; d.E = E; d.cnt = cnt; d.rank = rank;
        rg_preprocess<<<d.eEnd, 256, 0, stream>>>(d);
    }

    // ---- CSR scan ----
    const int nb = (N + 1023) / 1024;   // 49
    rg_scan_all<<<nb, 1024, 0, stream>>>(cnt, rowptr, bsums, bar, N, E, nb);

    const int rg8 = ((gN + 7) / 8) * 8;      // 392
    auto grid = [&](int MT) { return dim3(rg8 * MT); };
    const int gN64 = (N + 63) / 64;          // 782
    const int rg64 = ((gN64 + 7) / 8) * 8;   // 784
    const int gN2 = (N + 255) / 256;         // 196 (256-row tiles)
    const int rg256 = ((gN2 + 7) / 8) * 8;   // 200

    // L1: h1 = relu(A0 @ W1 + b1)   [N,1024]  + atomic-free scatter trailing
    {
        const int gemmBlocks = rg8 * 8;             // 3136
        const int scatBlocks = (E + 255) / 256;     // 3125
        rg_gemm_l1_scatter<<<dim3(gemmBlocks + scatBlocks), 256, 0, stream>>>(
            bufC, W1t, b1, 1024, bufA, N, 512, 1024, gN,
            gemmBlocks, ei, E, rowptr, rank, cols);
    }

    // L2: h2 = relu(h1 @ W2 + b2)   [N,1024]   (256^2 4-phase m201 schedule)
    rg_gemm256_8ph<true, 4><<<dim3(rg256 * 4), 512, 0, stream>>>(bufA, W2t, b2, bufB, N, Npad, 1024, 1024, gN2);
    // L3: h3 = relu(h2 @ W3 + b3)   [N,512]
    rg_gemm<true, true, false, false, 4><<<grid(4), 256, 0, stream>>>(bufB, W3t, b3, nullptr, 512, bufC, nullptr, N, 1024, 512, gN);
    // L4: pf = h3 @ W4 + b4  -> fp32 out_feat + bf16 padded [N,128]  (64-row)
    rg_gemm64<false, true, true, 1><<<dim3(rg64), 256, 0, stream>>>(bufC, W4t, b4, 80, bufA, out_feat, N, 512, 128, gN64);

    // 80-dim aggregation: s = pf + segsum(pf[src]) -> bufC[:, :128]
    rg_agg80<<<(N + 3) / 4, 256, 0, stream>>>(bufA, rowptr, cols, bufC, N);

    // L5: g = s @ Win + (1+deg)*bin  [N,512]
    rg_gemm<false, true, false, true, 4><<<grid(4), 256, 0, stream>>>(bufC, Wit, bi, cnt, 512, bufA, nullptr, N, 128, 512, gN);
    // L6: r1 = relu(g @ Wg1 + bg1)  [N,512]
    rg_gemm<true, true, false, false, 4><<<grid(4), 256, 0, stream>>>(bufA, Wg1t, bg1, nullptr, 512, bufB, nullptr, N, 512, 512, gN);
    // L7: g2 = r1 @ Wg2 + bg2       [N,512]
    rg_gemm<false, true, false, false, 4><<<grid(4), 256, 0, stream>>>(bufB, Wg2t, bg2, nullptr, 512, bufC, nullptr, N, 512, 512, gN);
    // L8: mask = g2 @ Wout + bout -> fp32 out_mask   (64-row)
    rg_gemm64<false, false, true, 1><<<dim3(rg64), 256, 0, stream>>>(bufC, Wot, bo, 80, nullptr, out_mask, N, 512, 128, gN64);
}